// Round 8
// baseline (704.939 us; speedup 1.0000x reference)
//
#include <hip/hip_runtime.h>
#include <hip/hip_bf16.h>

typedef __hip_bfloat16 bf16;
typedef unsigned short u16;
typedef unsigned int u32;

#define DD 128           // feature dim
#define NG 200           // graphs
#define NL 5             // GCN layers
#define BETA_F 0.007782140442054161f   // log(1/128 + 1)
#define BN_EPS_F 1e-5f
#define WSTRIDE 136      // padded W' row stride (bf16 elems); 128x136 per layer
#define WELEMS (DD * WSTRIDE)
#define CVT_BLOCKS 1024
#define RS 136           // LDS r-tile row stride (bf16 elems)
#define TM 16            // nodes per fused block: ONE node per 16-lane group
#define EC 8             // edge chunk depth (branchless, clamped padding)
#define NREP 8           // stats replication factor (atomic contention spread)
#define NRANGE 8         // node ranges for LDS histogram (12.5K nodes each)
#define NSLICE 16        // edge slices per range
#define HISTB (2 * NRANGE * NSLICE)   // 256 hist blocks
#define HRMAX 12800      // max nodes per range (LDS budget); N <= 102400

typedef __attribute__((ext_vector_type(8))) short bf16x8v;
typedef __attribute__((ext_vector_type(4))) float f32x4v;

__device__ __forceinline__ int range_size(int N) {
    return (((N + NRANGE - 1) / NRANGE) + 1) & ~1;   // even-rounded ceil
}

// ---- dtype-generic load/store helpers (flag-selected, wave-uniform) ----

template<typename T> struct LD;
template<> struct LD<float> {
    static __device__ __forceinline__ float f(const void* p, size_t i) {
        return ((const float*)p)[i];
    }
};
template<> struct LD<bf16> {
    static __device__ __forceinline__ float f(const void* p, size_t i) {
        return __bfloat162float(((const bf16*)p)[i]);
    }
};
template<typename T> struct ST;
template<> struct ST<float> {
    static __device__ __forceinline__ void s(void* p, size_t i, float v) {
        ((float*)p)[i] = v;
    }
};
template<> struct ST<bf16> {
    static __device__ __forceinline__ void s(void* p, size_t i, float v) {
        ((bf16*)p)[i] = __float2bfloat16(v);
    }
};

// ---------------- k_init: cvt + LDS-histogram (interleaved), prepw, bounds ----
template<typename TF>
__device__ __forceinline__ void prepw_body(int l, const void* gcn_w, const void* gcn_b,
        bf16* __restrict__ wtp, float* __restrict__ biasp) {
    int t = threadIdx.x;
    const TF* Wp = (const TF*)gcn_w + (size_t)l * DD * DD;
    const TF* bp = (const TF*)gcn_b + (size_t)l * DD;
    bf16* wo = wtp + (size_t)l * WELEMS;
    for (int idx = t; idx < DD * DD; idx += 256) {
        int k = idx >> 7, n = idx & 127;
        float wv = BETA_F * LD<TF>::f(Wp, idx) + (k == n ? (1.0f - BETA_F) : 0.0f);
        wo[n * WSTRIDE + k] = __float2bfloat16(wv);
    }
    if (t < DD) biasp[l * DD + t] = LD<TF>::f(bp, t);
}

__global__ void k_init(const int* __restrict__ src, const int* __restrict__ dst,
        u32* __restrict__ histg, int E, const u16* bn_g_raw, int* flag,
        const void* feat, const void* gcn_w, const void* gcn_b,
        const int* __restrict__ gid, int* gstart, bf16* wtp, float* biasp,
        bf16* hbuf, int N) {
    __shared__ u32 hl[HRMAX / 2];   // packed u16 histogram, 25.6 KB
    int b = blockIdx.x;
    int t = threadIdx.x;
    int bf = (bn_g_raw[0] == 0x3F80) ? 1 : 0;   // local detect (cached read)
    const int m = HISTB;            // HISTB < CVT_BLOCKS
    const int cvtHist = CVT_BLOCKS + HISTB;
    if (b < cvtHist) {
        int role, rid;
        if (b < 2 * m) { role = b & 1; rid = b >> 1; }
        else { role = 0; rid = m + (b - 2 * m); }
        if (role == 1) {
            // LDS histogram: (role2, range, slice) — zero global atomics
            int role2 = rid >> 7;          // 0: out-degree (src), 1: in-degree (dst)
            int rem = rid & 127;
            int r = rem >> 4, s = rem & 15;
            int RSZ = range_size(N);
            int base = r * RSZ;
            int hi = base + RSZ; if (hi > N) hi = N;
            int cnt = hi - base;
            int words = RSZ >> 1;
            for (int i = t; i < words; i += 256) hl[i] = 0;
            __syncthreads();
            const int* arr = role2 ? dst : src;
            int e0 = (int)((long)s * E / NSLICE);
            int e1 = (int)((long)(s + 1) * E / NSLICE);
            for (int e = e0 + t; e < e1; e += 256) {
                unsigned d = (unsigned)(arr[e] - base);
                if (d < (unsigned)cnt)
                    atomicAdd(&hl[d >> 1], 1u << ((d & 1) << 4));
            }
            __syncthreads();
            u32* out = histg + (size_t)(role2 * NSLICE + s) * ((size_t)(RSZ * NRANGE) >> 1)
                             + (base >> 1);
            for (int i = t; i < words; i += 256) out[i] = hl[i];
        } else {
            // cvt: only needed for f32 input (bf16 input is used in place)
            if (bf) return;
            int total8 = N * DD / 8;
            int i = rid * 256 + t;
            int stride = CVT_BLOCKS * 256;
            uint4* d = (uint4*)hbuf;
            const float4* s = (const float4*)feat;
            for (; i < total8; i += stride) {
                float4 x = s[2 * i], y = s[2 * i + 1];
                union { uint4 u; bf16 b8[8]; } o;
                o.b8[0] = __float2bfloat16(x.x); o.b8[1] = __float2bfloat16(x.y);
                o.b8[2] = __float2bfloat16(x.z); o.b8[3] = __float2bfloat16(x.w);
                o.b8[4] = __float2bfloat16(y.x); o.b8[5] = __float2bfloat16(y.y);
                o.b8[6] = __float2bfloat16(y.z); o.b8[7] = __float2bfloat16(y.w);
                d[i] = o.u;
            }
        }
        return;
    }
    b -= cvtHist;
    if (b < NL) {
        if (bf) prepw_body<bf16 >(b, gcn_w, gcn_b, wtp, biasp);
        else    prepw_body<float>(b, gcn_w, gcn_b, wtp, biasp);
        return;
    }
    // bounds + flag
    if (t == 0) *flag = bf;
    int g = t;
    if (g <= NG) {
        if (g == NG) gstart[NG] = N;
        else {
            int lo = 0, hi = N;
            while (lo < hi) { int mid = (lo + hi) >> 1; if (gid[mid] < g) lo = mid + 1; else hi = mid; }
            gstart[g] = lo;
        }
    }
}

// ---------------- scan (3-phase) + norm precompute (hist-slice summing) --------

__global__ void k_reduce_chunks(const u16* __restrict__ hist16, int* bsum, int N) {
    __shared__ int lds[256];
    int RSZ = range_size(N);
    size_t Npad = (size_t)RSZ * NRANGE;
    int base = blockIdx.x * 1024;
    int s = 0;
    #pragma unroll
    for (int k = 0; k < 4; ++k) {
        int i = base + threadIdx.x + k * 256;
        if (i < N) {
            int v = 0;
            #pragma unroll
            for (int sl = 0; sl < NSLICE; ++sl)
                v += hist16[(size_t)(NSLICE + sl) * Npad + i];
            s += v;
        }
    }
    lds[threadIdx.x] = s;
    __syncthreads();
    for (int off = 128; off > 0; off >>= 1) {
        if (threadIdx.x < off) lds[threadIdx.x] += lds[threadIdx.x + off];
        __syncthreads();
    }
    if (threadIdx.x == 0) bsum[blockIdx.x] = lds[0];
}

__global__ void k_scan_bsum(int* bsum, int B, int* row_ptr, int N, int E) {
    __shared__ int lds[128];
    int t = threadIdx.x;
    if (B > 128) {                       // fallback (not hit at this problem size)
        if (t == 0) {
            int acc = 0;
            for (int i = 0; i < B; ++i) { int v = bsum[i]; bsum[i] = acc; acc += v; }
            row_ptr[N] = E;
        }
        return;
    }
    int v = (t < B) ? bsum[t] : 0;
    lds[t] = v;
    __syncthreads();
    for (int off = 1; off < 128; off <<= 1) {
        int add = (t >= off) ? lds[t - off] : 0;
        __syncthreads();
        lds[t] += add;
        __syncthreads();
    }
    if (t < B) bsum[t] = (t > 0) ? lds[t - 1] : 0;   // exclusive
    if (t == 0) row_ptr[N] = E;
}

__global__ void k_scan_chunks(const u16* __restrict__ hist16,
                              const int* __restrict__ bsum, int* row_ptr,
                              float* norm_out, float* norm_in, int N) {
    __shared__ int lds[256];
    int RSZ = range_size(N);
    size_t Npad = (size_t)RSZ * NRANGE;
    int t = threadIdx.x;
    int base = blockIdx.x * 1024;
    int vals[4];
    int tsum = 0;
    #pragma unroll
    for (int k = 0; k < 4; ++k) {
        int i = base + t * 4 + k;
        int v = 0;
        if (i < N) {
            int doo = 0;
            #pragma unroll
            for (int sl = 0; sl < NSLICE; ++sl) {
                v   += hist16[(size_t)(NSLICE + sl) * Npad + i];
                doo += hist16[(size_t)sl * Npad + i];
            }
            norm_in[i] = rsqrtf((float)(v > 1 ? v : 1));
            norm_out[i] = rsqrtf((float)(doo > 1 ? doo : 1));
        }
        vals[k] = tsum;
        tsum += v;
    }
    lds[t] = tsum;
    __syncthreads();
    for (int off = 1; off < 256; off <<= 1) {
        int add = (t >= off) ? lds[t - off] : 0;
        __syncthreads();
        lds[t] += add;
        __syncthreads();
    }
    int toff = (t > 0 ? lds[t - 1] : 0) + bsum[blockIdx.x];
    #pragma unroll
    for (int k = 0; k < 4; ++k) {
        int i = base + t * 4 + k;
        if (i < N) row_ptr[i] = toff + vals[k];
    }
}

// ---- CSR fill with LDS cursors (no device atomics) ----
// Block (r, s): seeds cursors for its node range with row_ptr + sum of earlier
// slices' counts, then scans dst slice s claiming slots via LDS atomicAdd.
// Slot ranges are disjoint across blocks by construction -> exact CSR.
__global__ void k_fill(const int* __restrict__ src, const int* __restrict__ dst,
                       const u16* __restrict__ hist16, const int* __restrict__ row_ptr,
                       int* __restrict__ col, int E, int N) {
    __shared__ int cur[HRMAX];   // 51.2 KB
    int t = threadIdx.x;
    int r = blockIdx.x >> 4;     // NSLICE = 16
    int s = blockIdx.x & 15;
    int RSZ = range_size(N);
    size_t Npad = (size_t)RSZ * NRANGE;
    int base = r * RSZ;
    int hi = base + RSZ; if (hi > N) hi = N;
    int cnt = hi - base;
    for (int i = t; i < cnt; i += 256) {
        int c = row_ptr[base + i];
        for (int sp = 0; sp < s; ++sp)
            c += hist16[(size_t)(NSLICE + sp) * Npad + base + i];
        cur[i] = c;
    }
    __syncthreads();
    int e0 = (int)((long)s * E / NSLICE);
    int e1 = (int)((long)(s + 1) * E / NSLICE);
    for (int e = e0 + t; e < e1; e += 256) {
        unsigned off = (unsigned)(dst[e] - base);
        if (off < (unsigned)cnt) {
            int p = atomicAdd(&cur[off], 1);
            col[p] = src[e];
        }
    }
}

// ---------------- fused pool / gather+GEMM ----------------
// blocks [0,poolCnt): pool role. blocks [poolCnt,...): TM=16 nodes each,
// ONE node per 16-lane group. Phase A: per node, uniform EC=8-deep branchless
// edge chunks -> 8 independent 256B row loads in flight. Phase B: 16x128x128
// MFMA GEMM (wave w owns cols [32w,32w+32)), h_out + NREP-replicated stats.
template<typename TF>
__device__ __forceinline__ void fused_body(const bf16* __restrict__ h,
        const int* __restrict__ row_ptr, const int* __restrict__ col,
        const float* __restrict__ norm_out, const float* __restrict__ norm_in,
        const float* __restrict__ statsP, const void* gamma, const void* beta,
        int apply, const int* __restrict__ gstart, float* __restrict__ pooled_l,
        int poolCnt, const bf16* __restrict__ wt, const float* __restrict__ biasf,
        bf16* __restrict__ h_out, float* __restrict__ stats, int N,
        float* s_sc, float* s_sh, uint4* s_big4) {
    int t = threadIdx.x;
    if (t < DD) {
        float sc = 1.f, sh = 0.f;
        if (apply) {
            float m1 = 0.f, m2 = 0.f;
            #pragma unroll
            for (int r = 0; r < NREP; ++r) {
                m1 += statsP[r * 2 * DD + t];
                m2 += statsP[r * 2 * DD + DD + t];
            }
            float invN = 1.0f / (float)N;
            float mu = m1 * invN;
            float var = fmaxf(m2 * invN - mu * mu, 0.f);
            sc = rsqrtf(var + BN_EPS_F) * LD<TF>::f(gamma, t);
            sh = LD<TF>::f(beta, t) - mu * sc;
        }
        s_sc[t] = sc; s_sh[t] = sh;
    }
    __syncthreads();
    float lo = apply ? 0.f : -__builtin_inff();

    if (blockIdx.x < poolCnt) {
        // ---- pool role (red aliased into s_big4: 16*128*4 = 8KB) ----
        float (*red)[DD] = (float (*)[DD])s_big4;
        int g = blockIdx.x;
        int rlo = gstart[g], rhi = gstart[g + 1];
        int c = t & 15, rg = t >> 4;
        int d0 = c * 8;
        float sc8[8], sh8[8];
        #pragma unroll
        for (int j = 0; j < 8; ++j) { sc8[j] = s_sc[d0 + j]; sh8[j] = s_sh[d0 + j]; }
        float acc[8] = {0.f, 0.f, 0.f, 0.f, 0.f, 0.f, 0.f, 0.f};
        for (int i = rlo + rg; i < rhi; i += 16) {
            union { uint4 u; u16 us[8]; } v;
            v.u = *(const uint4*)(h + ((size_t)i << 7) + d0);
            #pragma unroll
            for (int j = 0; j < 8; ++j) {
                float f = __uint_as_float((u32)v.us[j] << 16) * sc8[j] + sh8[j];
                acc[j] += fmaxf(f, lo);
            }
        }
        #pragma unroll
        for (int j = 0; j < 8; ++j) red[rg][d0 + j] = acc[j];
        __syncthreads();
        if (t < DD) {
            float s = 0.f;
            #pragma unroll
            for (int k = 0; k < 16; ++k) s += red[k][t];
            pooled_l[g * DD + t] = s;
        }
        return;
    }

    // ---- phase A: gather into LDS r-tile (one node per 16-lane group) ----
    bf16* rt = (bf16*)s_big4;
    int grp = t >> 4, c = t & 15;
    int d0 = c << 3;
    float sc8[8], sh8[8];
    #pragma unroll
    for (int j = 0; j < 8; ++j) { sc8[j] = s_sc[d0 + j]; sh8[j] = s_sh[d0 + j]; }
    int nbase = (blockIdx.x - poolCnt) * TM;
    int node = nbase + grp;
    {
        union { uint4 u; bf16 b8[8]; } o;
        if (node < N) {
            int beg = row_ptr[node], end = row_ptr[node + 1];
            // self-row + norm_in issued early: overlap with edge chunk latency
            uint4 svu = *(const uint4*)(h + ((size_t)node << 7) + d0);
            float ni = 0.9f * norm_in[node];
            float acc[8] = {0.f, 0.f, 0.f, 0.f, 0.f, 0.f, 0.f, 0.f};
            #pragma unroll 1
            for (int e = beg; e < end; e += EC) {
                int cs[EC]; uint4 hv[EC]; float no[EC];
                #pragma unroll
                for (int k = 0; k < EC; ++k) {
                    int ee = e + k;
                    cs[k] = col[ee < end ? ee : end - 1];   // clamped (pad dupes last edge)
                }
                #pragma unroll
                for (int k = 0; k < EC; ++k)
                    hv[k] = *(const uint4*)(h + ((size_t)cs[k] << 7) + d0);
                #pragma unroll
                for (int k = 0; k < EC; ++k)
                    no[k] = (e + k < end) ? norm_out[cs[k]] : 0.f;  // zero-weight pad
                #pragma unroll
                for (int k = 0; k < EC; ++k) {
                    union { uint4 u; u16 us[8]; } v;
                    v.u = hv[k];
                    float nn = no[k];
                    #pragma unroll
                    for (int j = 0; j < 8; ++j) {
                        float f = __uint_as_float((u32)v.us[j] << 16) * sc8[j] + sh8[j];
                        acc[j] += fmaxf(f, lo) * nn;
                    }
                }
            }
            union { uint4 u; u16 us[8]; } sv;
            sv.u = svu;
            #pragma unroll
            for (int j = 0; j < 8; ++j) {
                float f = __uint_as_float((u32)sv.us[j] << 16) * sc8[j] + sh8[j];
                f = fmaxf(f, lo);
                o.b8[j] = __float2bfloat16(ni * acc[j] + 0.1f * f);
            }
        } else {
            o.u = make_uint4(0u, 0u, 0u, 0u);   // pad rows: zero (outputs masked anyway)
        }
        *(uint4*)(rt + (size_t)grp * RS + d0) = o.u;
    }
    __syncthreads();

    // ---- phase B: GEMM from LDS A-tile (M=16; wave w -> cols [32w, 32w+32)) ----
    int w = t >> 6, lane = t & 63;
    int q = lane >> 4, cc = lane & 15;
    f32x4v acc2[2];
    acc2[0] = (f32x4v){0.f, 0.f, 0.f, 0.f};
    acc2[1] = (f32x4v){0.f, 0.f, 0.f, 0.f};
    #pragma unroll
    for (int ks = 0; ks < 4; ++ks) {
        int k0 = ks * 32 + q * 8;
        union { uint4 u; bf16x8v v; } a0;
        a0.u = *(const uint4*)(rt + (size_t)cc * RS + k0);
        #pragma unroll
        for (int ct = 0; ct < 2; ++ct) {
            union { uint4 u; bf16x8v v; } bb;
            bb.u = *(const uint4*)(wt + (size_t)(w * 32 + ct * 16 + cc) * WSTRIDE + k0);
            acc2[ct] = __builtin_amdgcn_mfma_f32_16x16x32_bf16(a0.v, bb.v, acc2[ct], 0, 0, 0);
        }
    }
    // epilogue: C layout col = lane&15, row = quad*4 + reg  [m89-verified]
    // stats via NREP-replicated atomics (no LDS reduction pass needed)
    float* statsR = stats + (size_t)(blockIdx.x & (NREP - 1)) * 2 * DD;
    #pragma unroll
    for (int ct = 0; ct < 2; ++ct) {
        int coln = w * 32 + ct * 16 + cc;
        float bs = biasf[coln];
        float s1 = 0.f, s2 = 0.f;
        #pragma unroll
        for (int reg = 0; reg < 4; ++reg) {
            size_t row = (size_t)nbase + q * 4 + reg;
            float v = acc2[ct][reg] + bs;
            if (row < (size_t)N) {
                h_out[(row << 7) + coln] = __float2bfloat16(v);
                s1 += v;
                s2 += v * v;
            }
        }
        s1 += __shfl_xor(s1, 16, 64); s1 += __shfl_xor(s1, 32, 64);
        s2 += __shfl_xor(s2, 16, 64); s2 += __shfl_xor(s2, 32, 64);
        if (q == 0) {
            atomicAdd(&statsR[coln], s1);
            atomicAdd(&statsR[DD + coln], s2);
        }
    }
}

__global__ void k_fused(const bf16* __restrict__ h, const void* __restrict__ h0alt,
        int isL0, const int* __restrict__ row_ptr,
        const int* __restrict__ col, const float* __restrict__ norm_out,
        const float* __restrict__ norm_in, const float* __restrict__ statsP,
        const void* bn_g, const void* bn_b, int laff, int apply,
        const int* __restrict__ gstart, float* __restrict__ pooled_l, int poolCnt,
        const int* __restrict__ flag, const bf16* __restrict__ wt,
        const float* __restrict__ biasf, bf16* __restrict__ h_out,
        float* __restrict__ stats, int N) {
    __shared__ float s_sc[DD];
    __shared__ float s_sh[DD];
    __shared__ uint4 s_big4[512];   // 8KB: pool-red [16][128]f32 / gather r-tile [16][136]bf16
    int bfv = *flag;
    // bf16 input: layer 0 reads feat in place (no cvt copy)
    const bf16* hp = (isL0 && bfv) ? (const bf16*)h0alt : h;
    size_t esz = bfv ? 2u : 4u;
    const char* gp = (const char*)bn_g + (size_t)laff * DD * esz;
    const char* bp = (const char*)bn_b + (size_t)laff * DD * esz;
    if (bfv) fused_body<bf16 >(hp, row_ptr, col, norm_out, norm_in, statsP, gp, bp,
                               apply, gstart, pooled_l, poolCnt, wt, biasf, h_out, stats, N,
                               s_sc, s_sh, s_big4);
    else     fused_body<float>(hp, row_ptr, col, norm_out, norm_in, statsP, gp, bp,
                               apply, gstart, pooled_l, poolCnt, wt, biasf, h_out, stats, N,
                               s_sc, s_sh, s_big4);
}

// ---------------- head (parallelized over 128 dims) ----------------

template<typename TF>
__device__ __forceinline__ void head_body(const float* __restrict__ pooled,
        const void* lin_w, const void* lin_b, void* out,
        float* red, float* scv, float* lse) {
    int g = blockIdx.x;   // 200
    int t = threadIdx.x;  // 128
    float part[10] = {0.f, 0.f, 0.f, 0.f, 0.f, 0.f, 0.f, 0.f, 0.f, 0.f};
    float mp = 0.f;
    for (int l = 0; l < NL + 1; ++l) {
        float pl = pooled[(size_t)(l * NG + g) * DD + t];
        if (l > 0) mp += pl;
        #pragma unroll
        for (int o = 0; o < 10; ++o)
            part[o] += pl * LD<TF>::f(lin_w, (size_t)l * DD * 10 + (size_t)t * 10 + o);
    }
    #pragma unroll
    for (int o = 0; o < 10; ++o) red[t * 10 + o] = part[o];
    __syncthreads();
    for (int off = 64; off >= 1; off >>= 1) {
        if (t < off) {
            #pragma unroll
            for (int o = 0; o < 10; ++o) red[t * 10 + o] += red[(t + off) * 10 + o];
        }
        __syncthreads();
    }
    if (t < 10) {
        float s = red[t];
        for (int l = 0; l < NL + 1; ++l) s += LD<TF>::f(lin_b, l * 10 + t);
        scv[t] = s;
    }
    __syncthreads();
    if (t == 0) {
        float m = scv[0];
        for (int o = 1; o < 10; ++o) m = fmaxf(m, scv[o]);
        float su = 0.f;
        for (int o = 0; o < 10; ++o) su += expf(scv[o] - m);
        *lse = m + logf(su);
    }
    __syncthreads();
    if (t < 10) ST<TF>::s(out, g * 10 + t, scv[t] - *lse);
    ST<TF>::s(out, NG * 10 + (size_t)g * DD + t, mp * 0.2f);
}

__global__ void k_head(const float* __restrict__ pooled, const int* __restrict__ flag,
        const void* lin_w, const void* lin_b, void* out) {
    __shared__ float red[128 * 10];
    __shared__ float scv[10];
    __shared__ float lse;
    if (*flag) head_body<bf16 >(pooled, lin_w, lin_b, out, red, scv, &lse);
    else       head_body<float>(pooled, lin_w, lin_b, out, red, scv, &lse);
}

// ---------------- launch ----------------

extern "C" void kernel_launch(void* const* d_in, const int* in_sizes, int n_in,
                              void* d_out, int out_size, void* d_ws, size_t ws_size,
                              hipStream_t stream) {
    const void* feat  = d_in[0];
    const int*  src   = (const int*)d_in[1];
    const int*  dst   = (const int*)d_in[2];
    const int*  gid   = (const int*)d_in[3];
    const void* gcn_w = d_in[4];
    const void* gcn_b = d_in[5];
    const void* bn_g  = d_in[6];
    const void* bn_b  = d_in[7];
    const void* lin_w = d_in[8];
    const void* lin_b = d_in[9];
    const int N = in_sizes[0] / DD;   // 100000
    const int E = in_sizes[1];        // 600000
    const int Mpad = ((N + 127) / 128) * 128;
    const int RSZ = (((N + NRANGE - 1) / NRANGE) + 1) & ~1;
    const size_t Npad = (size_t)RSZ * NRANGE;

    char* wsb = (char*)d_ws;
    size_t off = 0;
    auto carve = [&](size_t bytes) -> void* {
        void* p = wsb + off;
        off = (off + bytes + 255) & ~(size_t)255;
        return p;
    };
    int*   flag     = (int*)carve(4);
    // zeroed region: statsAll only (hist planes are fully overwritten each run)
    float* statsAll = (float*)carve((size_t)NL * NREP * 2 * DD * 4);
    // un-zeroed scratch
    u32*   histg    = (u32*)carve((size_t)2 * NSLICE * Npad * 2);   // u16[2][16][Npad]
    int*   row_ptr  = (int*)carve((size_t)(N + 1) * 4);
    int*   col      = (int*)carve((size_t)E * 4);
    int*   bsum     = (int*)carve(1024 * 4);
    int*   gstart   = (int*)carve((size_t)(NG + 1) * 4);
    float* norm_out = (float*)carve((size_t)N * 4);
    float* norm_in  = (float*)carve((size_t)N * 4);
    bf16*  wtp      = (bf16*)carve((size_t)NL * WELEMS * 2);
    float* biasp    = (float*)carve((size_t)NL * DD * 4);
    float* pooled   = (float*)carve((size_t)(NL + 1) * NG * DD * 4);
    bf16*  hA       = (bf16*)carve((size_t)Mpad * DD * 2);
    bf16*  hB       = (bf16*)carve((size_t)Mpad * DD * 2);

    if (off > ws_size || RSZ > HRMAX) return;   // guard: leave d_out zeroed

    hipMemsetAsync(statsAll, 0, (size_t)NL * NREP * 2 * DD * 4, stream);

    k_init<<<CVT_BLOCKS + HISTB + NL + 1, 256, 0, stream>>>(
        src, dst, histg, E, (const u16*)bn_g, flag,
        feat, gcn_w, gcn_b, gid, gstart, wtp, biasp, hA, N);

    int B = (N + 1023) / 1024;
    k_reduce_chunks<<<B, 256, 0, stream>>>((const u16*)histg, bsum, N);
    k_scan_bsum<<<1, 128, 0, stream>>>(bsum, B, row_ptr, N, E);
    k_scan_chunks<<<B, 256, 0, stream>>>((const u16*)histg, bsum, row_ptr,
                                         norm_out, norm_in, N);
    k_fill<<<NRANGE * NSLICE, 256, 0, stream>>>(src, dst, (const u16*)histg,
                                                row_ptr, col, E, N);

    const int GBLK = (N + TM - 1) / TM;   // gather+gemm blocks: TM nodes each
    bf16* bufs[2] = { hA, hB };
    for (int l = 0; l < NL; ++l) {
        bf16* hin  = bufs[l & 1];
        bf16* hout = bufs[(l + 1) & 1];
        float* stats  = statsAll + (size_t)l * NREP * 2 * DD;                      // written by layer l
        float* statsP = statsAll + (size_t)(l > 0 ? l - 1 : 0) * NREP * 2 * DD;    // prev layer's
        k_fused<<<NG + GBLK, 256, 0, stream>>>(
            hin, feat, l == 0 ? 1 : 0, row_ptr, col, norm_out, norm_in, statsP,
            bn_g, bn_b, l > 0 ? l - 1 : 0, l > 0 ? 1 : 0, gstart,
            pooled + (size_t)l * NG * DD, NG, flag,
            wtp + (size_t)l * WELEMS, biasp + (size_t)l * DD, hout, stats, N);
    }

    // final pool: hidden_rep[NL] from layer NL-1 output (stats[NL-1], bn[NL-1]); pool-only grid
    k_fused<<<NG, 256, 0, stream>>>(
        bufs[NL & 1], feat, 0, row_ptr, col, norm_out, norm_in,
        statsAll + (size_t)(NL - 1) * NREP * 2 * DD, bn_g, bn_b, NL - 1, 1, gstart,
        pooled + (size_t)NL * NG * DD, NG, flag,
        wtp, biasp, bufs[(NL + 1) & 1], statsAll + (size_t)(NL - 1) * NREP * 2 * DD, N);

    k_head<<<NG, DD, 0, stream>>>(pooled, flag, lin_w, lin_b, d_out);
}

// Round 9
// 519.352 us; speedup vs baseline: 1.3573x; 1.3573x over previous
//
#include <hip/hip_runtime.h>
#include <hip/hip_bf16.h>

typedef __hip_bfloat16 bf16;
typedef unsigned short u16;
typedef unsigned int u32;

#define DD 128           // feature dim
#define NG 200           // graphs
#define NL 5             // GCN layers
#define BETA_F 0.007782140442054161f   // log(1/128 + 1)
#define BN_EPS_F 1e-5f
#define WSTRIDE 136      // padded W' row stride (bf16 elems); 128x136 per layer
#define WELEMS (DD * WSTRIDE)
#define CVT_BLOCKS 1024
#define RS 136           // LDS r-tile row stride (bf16 elems)
#define TM 16            // nodes per fused block: ONE node per 16-lane group
#define EC 8             // edge chunk depth (branchless, clamped padding)
#define NREP 8           // stats replication factor (atomic contention spread)
#define NRANGE 8         // node ranges for LDS histogram (12.5K nodes each)
#define NSLICE 32        // edge slices per range (256 fill blocks = 1/CU)
#define HISTB (2 * NRANGE * NSLICE)   // 512 hist blocks
#define HRMAX 12800      // max nodes per range (LDS budget); N <= 102400

typedef __attribute__((ext_vector_type(8))) short bf16x8v;
typedef __attribute__((ext_vector_type(4))) float f32x4v;

__device__ __forceinline__ int range_size(int N) {
    return (((N + NRANGE - 1) / NRANGE) + 3) & ~3;   // ceil, rounded to 4 (ushort4 align)
}

// ---- dtype-generic load/store helpers (flag-selected, wave-uniform) ----

template<typename T> struct LD;
template<> struct LD<float> {
    static __device__ __forceinline__ float f(const void* p, size_t i) {
        return ((const float*)p)[i];
    }
};
template<> struct LD<bf16> {
    static __device__ __forceinline__ float f(const void* p, size_t i) {
        return __bfloat162float(((const bf16*)p)[i]);
    }
};
template<typename T> struct ST;
template<> struct ST<float> {
    static __device__ __forceinline__ void s(void* p, size_t i, float v) {
        ((float*)p)[i] = v;
    }
};
template<> struct ST<bf16> {
    static __device__ __forceinline__ void s(void* p, size_t i, float v) {
        ((bf16*)p)[i] = __float2bfloat16(v);
    }
};

// ---------------- k_init: cvt + LDS-histogram (interleaved), prepw, bounds ----
template<typename TF>
__device__ __forceinline__ void prepw_body(int l, const void* gcn_w, const void* gcn_b,
        bf16* __restrict__ wtp, float* __restrict__ biasp) {
    int t = threadIdx.x;
    const TF* Wp = (const TF*)gcn_w + (size_t)l * DD * DD;
    const TF* bp = (const TF*)gcn_b + (size_t)l * DD;
    bf16* wo = wtp + (size_t)l * WELEMS;
    for (int idx = t; idx < DD * DD; idx += 256) {
        int k = idx >> 7, n = idx & 127;
        float wv = BETA_F * LD<TF>::f(Wp, idx) + (k == n ? (1.0f - BETA_F) : 0.0f);
        wo[n * WSTRIDE + k] = __float2bfloat16(wv);
    }
    if (t < DD) biasp[l * DD + t] = LD<TF>::f(bp, t);
}

__global__ void k_init(const int* __restrict__ src, const int* __restrict__ dst,
        u32* __restrict__ histg, int E, const u16* bn_g_raw, int* flag,
        const void* feat, const void* gcn_w, const void* gcn_b,
        const int* __restrict__ gid, int* gstart, bf16* wtp, float* biasp,
        bf16* hbuf, int N) {
    __shared__ u32 hl[HRMAX / 2];   // packed u16 histogram, 25.6 KB
    int b = blockIdx.x;
    int t = threadIdx.x;
    int bf = (bn_g_raw[0] == 0x3F80) ? 1 : 0;   // local detect (cached read)
    const int m = HISTB;            // HISTB < CVT_BLOCKS
    const int cvtHist = CVT_BLOCKS + HISTB;
    if (b < cvtHist) {
        int role, rid;
        if (b < 2 * m) { role = b & 1; rid = b >> 1; }
        else { role = 0; rid = m + (b - 2 * m); }
        if (role == 1) {
            // LDS histogram: (role2, range, slice) — zero global atomics
            int role2 = rid / (NRANGE * NSLICE);   // 0: out-degree (src), 1: in-degree (dst)
            int rem = rid % (NRANGE * NSLICE);
            int r = rem / NSLICE, s = rem % NSLICE;
            int RSZ = range_size(N);
            int base = r * RSZ;
            int hi = base + RSZ; if (hi > N) hi = N;
            int cnt = hi - base;
            int words = RSZ >> 1;
            for (int i = t; i < words; i += 256) hl[i] = 0;
            __syncthreads();
            const int* arr = role2 ? dst : src;
            int e0 = (int)((long)s * E / NSLICE);
            int e1 = (int)((long)(s + 1) * E / NSLICE);
            for (int e = e0 + t; e < e1; e += 256) {
                unsigned d = (unsigned)(arr[e] - base);
                if (d < (unsigned)cnt)
                    atomicAdd(&hl[d >> 1], 1u << ((d & 1) << 4));
            }
            __syncthreads();
            u32* out = histg + (size_t)(role2 * NSLICE + s) * ((size_t)(RSZ * NRANGE) >> 1)
                             + (base >> 1);
            for (int i = t; i < words; i += 256) out[i] = hl[i];
        } else {
            // cvt: only needed for f32 input (bf16 input is used in place)
            if (bf) return;
            int total8 = N * DD / 8;
            int i = rid * 256 + t;
            int stride = CVT_BLOCKS * 256;
            uint4* d = (uint4*)hbuf;
            const float4* s = (const float4*)feat;
            for (; i < total8; i += stride) {
                float4 x = s[2 * i], y = s[2 * i + 1];
                union { uint4 u; bf16 b8[8]; } o;
                o.b8[0] = __float2bfloat16(x.x); o.b8[1] = __float2bfloat16(x.y);
                o.b8[2] = __float2bfloat16(x.z); o.b8[3] = __float2bfloat16(x.w);
                o.b8[4] = __float2bfloat16(y.x); o.b8[5] = __float2bfloat16(y.y);
                o.b8[6] = __float2bfloat16(y.z); o.b8[7] = __float2bfloat16(y.w);
                d[i] = o.u;
            }
        }
        return;
    }
    b -= cvtHist;
    if (b < NL) {
        if (bf) prepw_body<bf16 >(b, gcn_w, gcn_b, wtp, biasp);
        else    prepw_body<float>(b, gcn_w, gcn_b, wtp, biasp);
        return;
    }
    // bounds + flag
    if (t == 0) *flag = bf;
    int g = t;
    if (g <= NG) {
        if (g == NG) gstart[NG] = N;
        else {
            int lo = 0, hi = N;
            while (lo < hi) { int mid = (lo + hi) >> 1; if (gid[mid] < g) lo = mid + 1; else hi = mid; }
            gstart[g] = lo;
        }
    }
}

// ---------------- scan (3-phase) + norm precompute (hist-slice summing) --------

__global__ void k_reduce_chunks(const u16* __restrict__ hist16, int* bsum, int N) {
    __shared__ int lds[256];
    int RSZ = range_size(N);
    size_t Npad = (size_t)RSZ * NRANGE;
    int base = blockIdx.x * 1024;
    int s = 0;
    #pragma unroll
    for (int k = 0; k < 4; ++k) {
        int i = base + threadIdx.x + k * 256;
        if (i < N) {
            int v = 0;
            #pragma unroll
            for (int sl = 0; sl < NSLICE; ++sl)
                v += hist16[(size_t)(NSLICE + sl) * Npad + i];
            s += v;
        }
    }
    lds[threadIdx.x] = s;
    __syncthreads();
    for (int off = 128; off > 0; off >>= 1) {
        if (threadIdx.x < off) lds[threadIdx.x] += lds[threadIdx.x + off];
        __syncthreads();
    }
    if (threadIdx.x == 0) bsum[blockIdx.x] = lds[0];
}

__global__ void k_scan_bsum(int* bsum, int B, int* row_ptr, int N, int E) {
    __shared__ int lds[128];
    int t = threadIdx.x;
    if (B > 128) {                       // fallback (not hit at this problem size)
        if (t == 0) {
            int acc = 0;
            for (int i = 0; i < B; ++i) { int v = bsum[i]; bsum[i] = acc; acc += v; }
            row_ptr[N] = E;
        }
        return;
    }
    int v = (t < B) ? bsum[t] : 0;
    lds[t] = v;
    __syncthreads();
    for (int off = 1; off < 128; off <<= 1) {
        int add = (t >= off) ? lds[t - off] : 0;
        __syncthreads();
        lds[t] += add;
        __syncthreads();
    }
    if (t < B) bsum[t] = (t > 0) ? lds[t - 1] : 0;   // exclusive
    if (t == 0) row_ptr[N] = E;
}

// Also converts the dst hist planes IN PLACE to per-node exclusive prefixes
// over slices (what k_fill needs for cursor seeding — kills its serial sp-loop).
// Prefix <= node in-degree << 65535, so u16 is safe.
__global__ void k_scan_chunks(u16* __restrict__ hist16,
                              const int* __restrict__ bsum, int* row_ptr,
                              float* norm_out, float* norm_in, int N) {
    __shared__ int lds[256];
    int RSZ = range_size(N);
    size_t Npad = (size_t)RSZ * NRANGE;
    int t = threadIdx.x;
    int base = blockIdx.x * 1024;
    int i0 = base + t * 4;
    int in4[4] = {0, 0, 0, 0};
    int out4[4] = {0, 0, 0, 0};
    if (i0 < N) {
        #pragma unroll 1
        for (int sl = 0; sl < NSLICE; ++sl) {
            u16* dp = hist16 + (size_t)(NSLICE + sl) * Npad + i0;
            const u16* sp = hist16 + (size_t)sl * Npad + i0;
            ushort4 hd = *(const ushort4*)dp;
            ushort4 hs = *(const ushort4*)sp;
            ushort4 p;
            p.x = (u16)in4[0]; p.y = (u16)in4[1]; p.z = (u16)in4[2]; p.w = (u16)in4[3];
            *(ushort4*)dp = p;   // exclusive prefix in place
            in4[0] += hd.x; in4[1] += hd.y; in4[2] += hd.z; in4[3] += hd.w;
            out4[0] += hs.x; out4[1] += hs.y; out4[2] += hs.z; out4[3] += hs.w;
        }
    }
    int vals[4];
    int tsum = 0;
    #pragma unroll
    for (int k = 0; k < 4; ++k) {
        int i = i0 + k;
        if (i < N) {
            norm_in[i] = rsqrtf((float)(in4[k] > 1 ? in4[k] : 1));
            norm_out[i] = rsqrtf((float)(out4[k] > 1 ? out4[k] : 1));
        }
        vals[k] = tsum;
        tsum += (i < N) ? in4[k] : 0;
    }
    lds[t] = tsum;
    __syncthreads();
    for (int off = 1; off < 256; off <<= 1) {
        int add = (t >= off) ? lds[t - off] : 0;
        __syncthreads();
        lds[t] += add;
        __syncthreads();
    }
    int toff = (t > 0 ? lds[t - 1] : 0) + bsum[blockIdx.x];
    #pragma unroll
    for (int k = 0; k < 4; ++k) {
        int i = i0 + k;
        if (i < N) row_ptr[i] = toff + vals[k];
    }
}

// ---- CSR fill with LDS cursors (no device atomics) ----
// Block (r, s): seeds cursors for its node range with row_ptr + slice-prefix
// (precomputed in k_scan_chunks — single coalesced read), then scans dst slice
// s claiming slots via LDS atomicAdd. Slot ranges disjoint by construction.
__global__ void k_fill(const int* __restrict__ src, const int* __restrict__ dst,
                       const u16* __restrict__ hist16, const int* __restrict__ row_ptr,
                       int* __restrict__ col, int E, int N) {
    __shared__ int cur[HRMAX];   // 51.2 KB
    int t = threadIdx.x;
    int r = blockIdx.x / NSLICE;
    int s = blockIdx.x % NSLICE;
    int RSZ = range_size(N);
    size_t Npad = (size_t)RSZ * NRANGE;
    int base = r * RSZ;
    int hi = base + RSZ; if (hi > N) hi = N;
    int cnt = hi - base;
    const u16* pref = hist16 + (size_t)(NSLICE + s) * Npad + base;
    for (int i = t; i < cnt; i += 256)
        cur[i] = row_ptr[base + i] + pref[i];
    __syncthreads();
    int e0 = (int)((long)s * E / NSLICE);
    int e1 = (int)((long)(s + 1) * E / NSLICE);
    for (int e = e0 + t; e < e1; e += 256) {
        unsigned off = (unsigned)(dst[e] - base);
        if (off < (unsigned)cnt) {
            int p = atomicAdd(&cur[off], 1);
            col[p] = src[e];
        }
    }
}

// ---------------- fused pool / gather+GEMM ----------------
// blocks [0,poolCnt): pool role. blocks [poolCnt,...): TM=16 nodes each,
// ONE node per 16-lane group. Phase A: per node, uniform EC=8-deep branchless
// edge chunks -> 8 independent 256B row loads in flight. Phase B: 16x128x128
// MFMA GEMM (wave w owns cols [32w,32w+32)), h_out + NREP-replicated stats.
template<typename TF>
__device__ __forceinline__ void fused_body(const bf16* __restrict__ h,
        const int* __restrict__ row_ptr, const int* __restrict__ col,
        const float* __restrict__ norm_out, const float* __restrict__ norm_in,
        const float* __restrict__ statsP, const void* gamma, const void* beta,
        int apply, const int* __restrict__ gstart, float* __restrict__ pooled_l,
        int poolCnt, const bf16* __restrict__ wt, const float* __restrict__ biasf,
        bf16* __restrict__ h_out, float* __restrict__ stats, int N,
        float* s_sc, float* s_sh, uint4* s_big4) {
    int t = threadIdx.x;
    if (t < DD) {
        float sc = 1.f, sh = 0.f;
        if (apply) {
            float m1 = 0.f, m2 = 0.f;
            #pragma unroll
            for (int r = 0; r < NREP; ++r) {
                m1 += statsP[r * 2 * DD + t];
                m2 += statsP[r * 2 * DD + DD + t];
            }
            float invN = 1.0f / (float)N;
            float mu = m1 * invN;
            float var = fmaxf(m2 * invN - mu * mu, 0.f);
            sc = rsqrtf(var + BN_EPS_F) * LD<TF>::f(gamma, t);
            sh = LD<TF>::f(beta, t) - mu * sc;
        }
        s_sc[t] = sc; s_sh[t] = sh;
    }
    __syncthreads();
    float lo = apply ? 0.f : -__builtin_inff();

    if (blockIdx.x < poolCnt) {
        // ---- pool role (red aliased into s_big4: 16*128*4 = 8KB) ----
        float (*red)[DD] = (float (*)[DD])s_big4;
        int g = blockIdx.x;
        int rlo = gstart[g], rhi = gstart[g + 1];
        int c = t & 15, rg = t >> 4;
        int d0 = c * 8;
        float sc8[8], sh8[8];
        #pragma unroll
        for (int j = 0; j < 8; ++j) { sc8[j] = s_sc[d0 + j]; sh8[j] = s_sh[d0 + j]; }
        float acc[8] = {0.f, 0.f, 0.f, 0.f, 0.f, 0.f, 0.f, 0.f};
        for (int i = rlo + rg; i < rhi; i += 16) {
            union { uint4 u; u16 us[8]; } v;
            v.u = *(const uint4*)(h + ((size_t)i << 7) + d0);
            #pragma unroll
            for (int j = 0; j < 8; ++j) {
                float f = __uint_as_float((u32)v.us[j] << 16) * sc8[j] + sh8[j];
                acc[j] += fmaxf(f, lo);
            }
        }
        #pragma unroll
        for (int j = 0; j < 8; ++j) red[rg][d0 + j] = acc[j];
        __syncthreads();
        if (t < DD) {
            float s = 0.f;
            #pragma unroll
            for (int k = 0; k < 16; ++k) s += red[k][t];
            pooled_l[g * DD + t] = s;
        }
        return;
    }

    // ---- phase A: gather into LDS r-tile (one node per 16-lane group) ----
    bf16* rt = (bf16*)s_big4;
    int grp = t >> 4, c = t & 15;
    int d0 = c << 3;
    float sc8[8], sh8[8];
    #pragma unroll
    for (int j = 0; j < 8; ++j) { sc8[j] = s_sc[d0 + j]; sh8[j] = s_sh[d0 + j]; }
    int nbase = (blockIdx.x - poolCnt) * TM;
    int node = nbase + grp;
    {
        union { uint4 u; bf16 b8[8]; } o;
        if (node < N) {
            int beg = row_ptr[node], end = row_ptr[node + 1];
            // self-row + norm_in issued early: overlap with edge chunk latency
            uint4 svu = *(const uint4*)(h + ((size_t)node << 7) + d0);
            float ni = 0.9f * norm_in[node];
            float acc[8] = {0.f, 0.f, 0.f, 0.f, 0.f, 0.f, 0.f, 0.f};
            #pragma unroll 1
            for (int e = beg; e < end; e += EC) {
                int cs[EC]; uint4 hv[EC]; float no[EC];
                #pragma unroll
                for (int k = 0; k < EC; ++k) {
                    int ee = e + k;
                    cs[k] = col[ee < end ? ee : end - 1];   // clamped (pad dupes last edge)
                }
                #pragma unroll
                for (int k = 0; k < EC; ++k)
                    hv[k] = *(const uint4*)(h + ((size_t)cs[k] << 7) + d0);
                #pragma unroll
                for (int k = 0; k < EC; ++k)
                    no[k] = (e + k < end) ? norm_out[cs[k]] : 0.f;  // zero-weight pad
                #pragma unroll
                for (int k = 0; k < EC; ++k) {
                    union { uint4 u; u16 us[8]; } v;
                    v.u = hv[k];
                    float nn = no[k];
                    #pragma unroll
                    for (int j = 0; j < 8; ++j) {
                        float f = __uint_as_float((u32)v.us[j] << 16) * sc8[j] + sh8[j];
                        acc[j] += fmaxf(f, lo) * nn;
                    }
                }
            }
            union { uint4 u; u16 us[8]; } sv;
            sv.u = svu;
            #pragma unroll
            for (int j = 0; j < 8; ++j) {
                float f = __uint_as_float((u32)sv.us[j] << 16) * sc8[j] + sh8[j];
                f = fmaxf(f, lo);
                o.b8[j] = __float2bfloat16(ni * acc[j] + 0.1f * f);
            }
        } else {
            o.u = make_uint4(0u, 0u, 0u, 0u);   // pad rows: zero (outputs masked anyway)
        }
        *(uint4*)(rt + (size_t)grp * RS + d0) = o.u;
    }
    __syncthreads();

    // ---- phase B: GEMM from LDS A-tile (M=16; wave w -> cols [32w, 32w+32)) ----
    int w = t >> 6, lane = t & 63;
    int q = lane >> 4, cc = lane & 15;
    f32x4v acc2[2];
    acc2[0] = (f32x4v){0.f, 0.f, 0.f, 0.f};
    acc2[1] = (f32x4v){0.f, 0.f, 0.f, 0.f};
    #pragma unroll
    for (int ks = 0; ks < 4; ++ks) {
        int k0 = ks * 32 + q * 8;
        union { uint4 u; bf16x8v v; } a0;
        a0.u = *(const uint4*)(rt + (size_t)cc * RS + k0);
        #pragma unroll
        for (int ct = 0; ct < 2; ++ct) {
            union { uint4 u; bf16x8v v; } bb;
            bb.u = *(const uint4*)(wt + (size_t)(w * 32 + ct * 16 + cc) * WSTRIDE + k0);
            acc2[ct] = __builtin_amdgcn_mfma_f32_16x16x32_bf16(a0.v, bb.v, acc2[ct], 0, 0, 0);
        }
    }
    // epilogue: C layout col = lane&15, row = quad*4 + reg  [m89-verified]
    // stats via NREP-replicated atomics (no LDS reduction pass needed)
    float* statsR = stats + (size_t)(blockIdx.x & (NREP - 1)) * 2 * DD;
    #pragma unroll
    for (int ct = 0; ct < 2; ++ct) {
        int coln = w * 32 + ct * 16 + cc;
        float bs = biasf[coln];
        float s1 = 0.f, s2 = 0.f;
        #pragma unroll
        for (int reg = 0; reg < 4; ++reg) {
            size_t row = (size_t)nbase + q * 4 + reg;
            float v = acc2[ct][reg] + bs;
            if (row < (size_t)N) {
                h_out[(row << 7) + coln] = __float2bfloat16(v);
                s1 += v;
                s2 += v * v;
            }
        }
        s1 += __shfl_xor(s1, 16, 64); s1 += __shfl_xor(s1, 32, 64);
        s2 += __shfl_xor(s2, 16, 64); s2 += __shfl_xor(s2, 32, 64);
        if (q == 0) {
            atomicAdd(&statsR[coln], s1);
            atomicAdd(&statsR[DD + coln], s2);
        }
    }
}

__global__ void k_fused(const bf16* __restrict__ h, const void* __restrict__ h0alt,
        int isL0, const int* __restrict__ row_ptr,
        const int* __restrict__ col, const float* __restrict__ norm_out,
        const float* __restrict__ norm_in, const float* __restrict__ statsP,
        const void* bn_g, const void* bn_b, int laff, int apply,
        const int* __restrict__ gstart, float* __restrict__ pooled_l, int poolCnt,
        const int* __restrict__ flag, const bf16* __restrict__ wt,
        const float* __restrict__ biasf, bf16* __restrict__ h_out,
        float* __restrict__ stats, int N) {
    __shared__ float s_sc[DD];
    __shared__ float s_sh[DD];
    __shared__ uint4 s_big4[512];   // 8KB: pool-red [16][128]f32 / gather r-tile [16][136]bf16
    int bfv = *flag;
    // bf16 input: layer 0 reads feat in place (no cvt copy)
    const bf16* hp = (isL0 && bfv) ? (const bf16*)h0alt : h;
    size_t esz = bfv ? 2u : 4u;
    const char* gp = (const char*)bn_g + (size_t)laff * DD * esz;
    const char* bp = (const char*)bn_b + (size_t)laff * DD * esz;
    if (bfv) fused_body<bf16 >(hp, row_ptr, col, norm_out, norm_in, statsP, gp, bp,
                               apply, gstart, pooled_l, poolCnt, wt, biasf, h_out, stats, N,
                               s_sc, s_sh, s_big4);
    else     fused_body<float>(hp, row_ptr, col, norm_out, norm_in, statsP, gp, bp,
                               apply, gstart, pooled_l, poolCnt, wt, biasf, h_out, stats, N,
                               s_sc, s_sh, s_big4);
}

// ---------------- head (parallelized over 128 dims) ----------------

template<typename TF>
__device__ __forceinline__ void head_body(const float* __restrict__ pooled,
        const void* lin_w, const void* lin_b, void* out,
        float* red, float* scv, float* lse) {
    int g = blockIdx.x;   // 200
    int t = threadIdx.x;  // 128
    float part[10] = {0.f, 0.f, 0.f, 0.f, 0.f, 0.f, 0.f, 0.f, 0.f, 0.f};
    float mp = 0.f;
    for (int l = 0; l < NL + 1; ++l) {
        float pl = pooled[(size_t)(l * NG + g) * DD + t];
        if (l > 0) mp += pl;
        #pragma unroll
        for (int o = 0; o < 10; ++o)
            part[o] += pl * LD<TF>::f(lin_w, (size_t)l * DD * 10 + (size_t)t * 10 + o);
    }
    #pragma unroll
    for (int o = 0; o < 10; ++o) red[t * 10 + o] = part[o];
    __syncthreads();
    for (int off = 64; off >= 1; off >>= 1) {
        if (t < off) {
            #pragma unroll
            for (int o = 0; o < 10; ++o) red[t * 10 + o] += red[(t + off) * 10 + o];
        }
        __syncthreads();
    }
    if (t < 10) {
        float s = red[t];
        for (int l = 0; l < NL + 1; ++l) s += LD<TF>::f(lin_b, l * 10 + t);
        scv[t] = s;
    }
    __syncthreads();
    if (t == 0) {
        float m = scv[0];
        for (int o = 1; o < 10; ++o) m = fmaxf(m, scv[o]);
        float su = 0.f;
        for (int o = 0; o < 10; ++o) su += expf(scv[o] - m);
        *lse = m + logf(su);
    }
    __syncthreads();
    if (t < 10) ST<TF>::s(out, g * 10 + t, scv[t] - *lse);
    ST<TF>::s(out, NG * 10 + (size_t)g * DD + t, mp * 0.2f);
}

__global__ void k_head(const float* __restrict__ pooled, const int* __restrict__ flag,
        const void* lin_w, const void* lin_b, void* out) {
    __shared__ float red[128 * 10];
    __shared__ float scv[10];
    __shared__ float lse;
    if (*flag) head_body<bf16 >(pooled, lin_w, lin_b, out, red, scv, &lse);
    else       head_body<float>(pooled, lin_w, lin_b, out, red, scv, &lse);
}

// ---------------- launch ----------------

extern "C" void kernel_launch(void* const* d_in, const int* in_sizes, int n_in,
                              void* d_out, int out_size, void* d_ws, size_t ws_size,
                              hipStream_t stream) {
    const void* feat  = d_in[0];
    const int*  src   = (const int*)d_in[1];
    const int*  dst   = (const int*)d_in[2];
    const int*  gid   = (const int*)d_in[3];
    const void* gcn_w = d_in[4];
    const void* gcn_b = d_in[5];
    const void* bn_g  = d_in[6];
    const void* bn_b  = d_in[7];
    const void* lin_w = d_in[8];
    const void* lin_b = d_in[9];
    const int N = in_sizes[0] / DD;   // 100000
    const int E = in_sizes[1];        // 600000
    const int Mpad = ((N + 127) / 128) * 128;
    const int RSZ = (((N + NRANGE - 1) / NRANGE) + 3) & ~3;
    const size_t Npad = (size_t)RSZ * NRANGE;

    char* wsb = (char*)d_ws;
    size_t off = 0;
    auto carve = [&](size_t bytes) -> void* {
        void* p = wsb + off;
        off = (off + bytes + 255) & ~(size_t)255;
        return p;
    };
    int*   flag     = (int*)carve(4);
    // zeroed region: statsAll only (hist planes are fully overwritten each run)
    float* statsAll = (float*)carve((size_t)NL * NREP * 2 * DD * 4);
    // un-zeroed scratch
    u32*   histg    = (u32*)carve((size_t)2 * NSLICE * Npad * 2);   // u16[2][NSLICE][Npad]
    int*   row_ptr  = (int*)carve((size_t)(N + 1) * 4);
    int*   col      = (int*)carve((size_t)E * 4);
    int*   bsum     = (int*)carve(1024 * 4);
    int*   gstart   = (int*)carve((size_t)(NG + 1) * 4);
    float* norm_out = (float*)carve((size_t)N * 4);
    float* norm_in  = (float*)carve((size_t)N * 4);
    bf16*  wtp      = (bf16*)carve((size_t)NL * WELEMS * 2);
    float* biasp    = (float*)carve((size_t)NL * DD * 4);
    float* pooled   = (float*)carve((size_t)(NL + 1) * NG * DD * 4);
    bf16*  hA       = (bf16*)carve((size_t)Mpad * DD * 2);
    bf16*  hB       = (bf16*)carve((size_t)Mpad * DD * 2);

    if (off > ws_size || RSZ > HRMAX) return;   // guard: leave d_out zeroed

    hipMemsetAsync(statsAll, 0, (size_t)NL * NREP * 2 * DD * 4, stream);

    k_init<<<CVT_BLOCKS + HISTB + NL + 1, 256, 0, stream>>>(
        src, dst, histg, E, (const u16*)bn_g, flag,
        feat, gcn_w, gcn_b, gid, gstart, wtp, biasp, hA, N);

    int B = (N + 1023) / 1024;
    k_reduce_chunks<<<B, 256, 0, stream>>>((const u16*)histg, bsum, N);
    k_scan_bsum<<<1, 128, 0, stream>>>(bsum, B, row_ptr, N, E);
    k_scan_chunks<<<B, 256, 0, stream>>>((u16*)histg, bsum, row_ptr,
                                         norm_out, norm_in, N);
    k_fill<<<NRANGE * NSLICE, 256, 0, stream>>>(src, dst, (const u16*)histg,
                                                row_ptr, col, E, N);

    const int GBLK = (N + TM - 1) / TM;   // gather+gemm blocks: TM nodes each
    bf16* bufs[2] = { hA, hB };
    for (int l = 0; l < NL; ++l) {
        bf16* hin  = bufs[l & 1];
        bf16* hout = bufs[(l + 1) & 1];
        float* stats  = statsAll + (size_t)l * NREP * 2 * DD;                      // written by layer l
        float* statsP = statsAll + (size_t)(l > 0 ? l - 1 : 0) * NREP * 2 * DD;    // prev layer's
        k_fused<<<NG + GBLK, 256, 0, stream>>>(
            hin, feat, l == 0 ? 1 : 0, row_ptr, col, norm_out, norm_in, statsP,
            bn_g, bn_b, l > 0 ? l - 1 : 0, l > 0 ? 1 : 0, gstart,
            pooled + (size_t)l * NG * DD, NG, flag,
            wtp + (size_t)l * WELEMS, biasp + (size_t)l * DD, hout, stats, N);
    }

    // final pool: hidden_rep[NL] from layer NL-1 output (stats[NL-1], bn[NL-1]); pool-only grid
    k_fused<<<NG, 256, 0, stream>>>(
        bufs[NL & 1], feat, 0, row_ptr, col, norm_out, norm_in,
        statsAll + (size_t)(NL - 1) * NREP * 2 * DD, bn_g, bn_b, NL - 1, 1, gstart,
        pooled + (size_t)NL * NG * DD, NG, flag,
        wtp, biasp, bufs[(NL + 1) & 1], statsAll + (size_t)(NL - 1) * NREP * 2 * DD, N);

    k_head<<<NG, DD, 0, stream>>>(pooled, flag, lin_w, lin_b, d_out);
}